// Round 2
// baseline (289.477 us; speedup 1.0000x reference)
//
#include <hip/hip_runtime.h>
#include <hip/hip_bf16.h>

#define N_NODES   100000
#define N_EDGES   1600000
#define N_ETYPES  3
#define IN_FEATS  128
#define HEADS     4
#define OUT_FEATS 16
#define EDGE_FEATS 64
#define HD        64            // HEADS*OUT_FEATS
#define NEG_SLOPE 0.2f
#define MAXD_LDS  128           // agg fast-path max degree (Poisson(16): P(>128)~0)

#define NBUCK     800           // buckets for counting sort
#define NPB       125           // nodes per bucket (800*125 = N_NODES)
#define PBLK      400           // blocks in hist/scatter passes
#define EPB       4000          // edges per block (400*4000 = N_EDGES)
#define BCAP      2560          // LDS stage capacity in bucket_csr (mean 2000, std ~45)

typedef short s16x8 __attribute__((ext_vector_type(8)));
typedef float f32x4 __attribute__((ext_vector_type(4)));

__device__ __forceinline__ short f2bs(float f) {
    __hip_bfloat16 h = __float2bfloat16(f);
    return *reinterpret_cast<short*>(&h);
}

// ---------------------------------------------------------------------------
// Prep: WT bf16 [64][128]  (WT[n][k] = W[k][n])
// ---------------------------------------------------------------------------
__global__ __launch_bounds__(256) void wt_prep_kernel(
    const float* __restrict__ W, short* __restrict__ WTb)
{
    const int t = blockIdx.x * 256 + threadIdx.x;   // 0..8191
    const int k = t >> 6, n = t & 63;
    WTb[n * IN_FEATS + k] = f2bs(W[t]);
}

// ---------------------------------------------------------------------------
// Kernel A (MFMA): feat = x @ W, bf16 store, fused el/er.
// ---------------------------------------------------------------------------
#define XS_STRIDE 136   // 128 + 8 pad shorts
__global__ __launch_bounds__(256) void feat_el_er_kernel(
    const float* __restrict__ x,
    const short* __restrict__ WTb,
    const float* __restrict__ attn_l,
    const float* __restrict__ attn_r,
    __hip_bfloat16* __restrict__ featb,
    float* __restrict__ el,
    float* __restrict__ er)
{
    __shared__ short Xs[16 * XS_STRIDE];
    __shared__ short Ws[64 * XS_STRIDE];

    const int t = threadIdx.x;
    const int row0 = blockIdx.x * 16;
    {   // stage x -> bf16 LDS
        const int r = t >> 4, k0 = (t & 15) * 8;
        const float4* xg = (const float4*)(x + (size_t)(row0 + r) * IN_FEATS + k0);
        const float4 v0 = xg[0], v1 = xg[1];
        s16x8 p;
        p[0] = f2bs(v0.x); p[1] = f2bs(v0.y); p[2] = f2bs(v0.z); p[3] = f2bs(v0.w);
        p[4] = f2bs(v1.x); p[5] = f2bs(v1.y); p[6] = f2bs(v1.z); p[7] = f2bs(v1.w);
        *(s16x8*)&Xs[r * XS_STRIDE + k0] = p;
    }
    {   // stage WT bf16
#pragma unroll
        for (int j = 0; j < 4; ++j) {
            const int u = t + 256 * j;
            const int r = u >> 4, c = (u & 15) * 8;
            *(s16x8*)&Ws[r * XS_STRIDE + c] = *(const s16x8*)(WTb + r * IN_FEATS + c);
        }
    }
    __syncthreads();

    const int w    = t >> 6;
    const int lane = t & 63;
    const int m    = lane & 15;
    const int q    = lane >> 4;

    f32x4 acc = {0.f, 0.f, 0.f, 0.f};
#pragma unroll
    for (int kb = 0; kb < 4; ++kb) {
        const s16x8 af = *(const s16x8*)&Xs[m * XS_STRIDE + kb * 32 + q * 8];
        const s16x8 bf = *(const s16x8*)&Ws[(w * 16 + m) * XS_STRIDE + kb * 32 + q * 8];
        acc = __builtin_amdgcn_mfma_f32_16x16x32_bf16(af, bf, acc, 0, 0, 0);
    }

    const float al = attn_l[w * OUT_FEATS + m];
    const float ar = attn_r[w * OUT_FEATS + m];
#pragma unroll
    for (int r = 0; r < 4; ++r) {
        const int row = row0 + q * 4 + r;
        featb[(size_t)row * HD + w * 16 + m] = __float2bfloat16(acc[r]);
        float cl = acc[r] * al;
        float cr = acc[r] * ar;
#pragma unroll
        for (int msk = 1; msk < 16; msk <<= 1) {
            cl += __shfl_xor(cl, msk, 64);
            cr += __shfl_xor(cr, msk, 64);
        }
        if (m == 0) {
            el[row * HEADS + w] = cl;
            er[row * HEADS + w] = cr;
        }
    }
}

// ---------------------------------------------------------------------------
// Kernel B: ee[t,h] (12 scalars)
// ---------------------------------------------------------------------------
__global__ __launch_bounds__(64) void ee_kernel(
    const float* __restrict__ edge_emb,
    const float* __restrict__ W_e,
    const float* __restrict__ attn_e,
    float* __restrict__ ee)
{
    const int b  = blockIdx.x;
    const int ty = b >> 2;
    const int h  = b & 3;
    const int e  = threadIdx.x;

    float ef = 0.f;
#pragma unroll
    for (int k = 0; k < EDGE_FEATS; ++k)
        ef += edge_emb[ty * EDGE_FEATS + k] *
              W_e[k * (HEADS * EDGE_FEATS) + h * EDGE_FEATS + e];
    float v = ef * attn_e[h * EDGE_FEATS + e];
#pragma unroll
    for (int m = 1; m < 64; m <<= 1) v += __shfl_xor(v, m, 64);
    if (e == 0) ee[ty * HEADS + h] = v;
}

// ---------------------------------------------------------------------------
// CSR build via bucketed counting sort — all hot atomics in LDS.
// ---------------------------------------------------------------------------
__global__ __launch_bounds__(256) void bucket_hist_kernel(
    const int* __restrict__ dst, int* __restrict__ bhist)
{
    __shared__ int h[NBUCK];
    const int t = threadIdx.x, b = blockIdx.x;
    for (int j = t; j < NBUCK; j += 256) h[j] = 0;
    __syncthreads();
    const int e0 = b * EPB;
    for (int i = t; i < EPB; i += 256)
        atomicAdd(&h[dst[e0 + i] / NPB], 1);
    __syncthreads();
    for (int j = t; j < NBUCK; j += 256) bhist[b * NBUCK + j] = h[j];
}

// per bucket j, exclusive scan over blocks; btot[j] = total.
__global__ __launch_bounds__(256) void bucket_scan1_kernel(
    int* __restrict__ bhist, int* __restrict__ btot)
{
    __shared__ int sh[PBLK];
    const int t = threadIdx.x, j = blockIdx.x;
    const int j0 = t, j1 = t + 256;
    int o0 = 0, o1 = 0;
    if (j0 < PBLK) { o0 = bhist[j0 * NBUCK + j]; sh[j0] = o0; }
    if (j1 < PBLK) { o1 = bhist[j1 * NBUCK + j]; sh[j1] = o1; }
    __syncthreads();
    for (int off = 1; off < PBLK; off <<= 1) {
        int v0 = (j0 >= off && j0 < PBLK) ? sh[j0 - off] : 0;
        int v1 = (j1 >= off && j1 < PBLK) ? sh[j1 - off] : 0;
        __syncthreads();
        if (j0 < PBLK) sh[j0] += v0;
        if (j1 < PBLK) sh[j1] += v1;
        __syncthreads();
    }
    if (j0 < PBLK) bhist[j0 * NBUCK + j] = sh[j0] - o0;
    if (j1 < PBLK) bhist[j1 * NBUCK + j] = sh[j1] - o1;
    if (t == 255) btot[j] = sh[PBLK - 1];
}

// single block: exclusive scan btot[NBUCK] -> bbase[NBUCK+1]
__global__ __launch_bounds__(1024) void bucket_scan2_kernel(
    const int* __restrict__ btot, int* __restrict__ bbase)
{
    __shared__ int sh[NBUCK];
    const int t = threadIdx.x;
    int o = 0;
    if (t < NBUCK) { o = btot[t]; sh[t] = o; }
    __syncthreads();
    for (int off = 1; off < NBUCK; off <<= 1) {
        int v = (t >= off && t < NBUCK) ? sh[t - off] : 0;
        __syncthreads();
        if (t < NBUCK) sh[t] += v;
        __syncthreads();
    }
    if (t < NBUCK) bbase[t] = sh[t] - o;
    if (t == NBUCK - 1) bbase[NBUCK] = sh[t];
}

// scatter edges into bucket regions; LDS running counters.
// payload: {src, e | ty<<21 | ldst<<23}  (e:21b, ty:2b, ldst:7b)
__global__ __launch_bounds__(256) void bucket_scatter_kernel(
    const int* __restrict__ src, const int* __restrict__ dst,
    const int* __restrict__ etype,
    const int* __restrict__ bhist, const int* __restrict__ bbase,
    int2* __restrict__ sc_bucket)
{
    __shared__ int cnt[NBUCK];
    const int t = threadIdx.x, b = blockIdx.x;
    for (int j = t; j < NBUCK; j += 256)
        cnt[j] = bbase[j] + bhist[b * NBUCK + j];
    __syncthreads();
    const int e0 = b * EPB;
    for (int i = t; i < EPB; i += 256) {
        const int e  = e0 + i;
        const int dn = dst[e];
        const int bu = dn / NPB;
        const int ld = dn - bu * NPB;
        const int slot = atomicAdd(&cnt[bu], 1);
        sc_bucket[slot] = make_int2(src[e], e | (etype[e] << 21) | (ld << 23));
    }
}

// one block per bucket: LDS-stage edges (single global read), bin over 125
// local nodes in LDS, emit ptr + final CSR {src, e | ty<<24}.
__global__ __launch_bounds__(256) void bucket_csr_kernel(
    const int2* __restrict__ sc_bucket, const int* __restrict__ bbase,
    int* __restrict__ ptr, int2* __restrict__ sc_csr)
{
    __shared__ int2 sbuf[BCAP];      // 20.5 KB
    __shared__ int sdeg[128];
    __shared__ int scur[128];
    const int t = threadIdx.x, b = blockIdx.x;
    const int lo = bbase[b];
    const int count = bbase[b + 1] - lo;
    const bool staged = (count <= BCAP);

    if (t < 128) sdeg[t] = 0;
    __syncthreads();
    if (staged) {
        for (int i = t; i < count; i += 256) {
            const int2 v = sc_bucket[lo + i];
            sbuf[i] = v;
            atomicAdd(&sdeg[(v.y >> 23) & 0x7F], 1);
        }
    } else {
        for (int i = t; i < count; i += 256)
            atomicAdd(&sdeg[(sc_bucket[lo + i].y >> 23) & 0x7F], 1);
    }
    __syncthreads();
    // exclusive scan over 128 (125 used)
    const int orig = (t < 128) ? sdeg[t] : 0;
    for (int off = 1; off < 128; off <<= 1) {
        const int v = (t < 128 && t >= off) ? sdeg[t - off] : 0;
        __syncthreads();
        if (t < 128) sdeg[t] += v;
        __syncthreads();
    }
    if (t < 128) {
        const int excl = sdeg[t] - orig;
        if (t < NPB) ptr[b * NPB + t] = lo + excl;
        scur[t] = lo + excl;             // global slot base
    }
    if (b == 0 && t == 0) ptr[N_NODES] = N_EDGES;
    __syncthreads();
    if (staged) {
        for (int i = t; i < count; i += 256) {
            const int2 v = sbuf[i];
            const int ld = (v.y >> 23) & 0x7F;
            const int slot = atomicAdd(&scur[ld], 1);
            sc_csr[slot] = make_int2(v.x, (v.y & 0x1FFFFF) | (((v.y >> 21) & 3) << 24));
        }
    } else {
        for (int i = t; i < count; i += 256) {
            const int2 v = sc_bucket[lo + i];
            const int ld = (v.y >> 23) & 0x7F;
            const int slot = atomicAdd(&scur[ld], 1);
            sc_csr[slot] = make_int2(v.x, (v.y & 0x1FFFFF) | (((v.y >> 21) & 3) << 24));
        }
    }
}

// ---------------------------------------------------------------------------
// Kernel C: per-dst aggregation, one wave per node, two in-wave phases.
// Phase 1: 1 lane per (edge,head) -> exp computed exactly ONCE per (e,h);
//          w -> LDS, src -> LDS, z reduced per head. (16 edges/iter)
// Phase 2: quarter-wave per edge (4 edges in flight), 8B feat loads,
//          w broadcast from LDS; rst = acc * inv_z (normalization commutes).
// a_out moved to a separate coalesced kernel (attn_out_kernel): agg only
// emits inv_z per (node,head) -> kills scattered 16B writes + epilogue.
// ---------------------------------------------------------------------------
__global__ __launch_bounds__(256) void agg_kernel(
    const int2* __restrict__ sc_csr, const int* __restrict__ ptr,
    const float* __restrict__ el, const float* __restrict__ er,
    const float* __restrict__ ee, const __hip_bfloat16* __restrict__ featb,
    float* __restrict__ rst, float* __restrict__ invz)
{
    __shared__ float w_lds[4][MAXD_LDS * HEADS];   // 8 KB
    __shared__ int   s_lds[4][MAXD_LDS];           // 2 KB
    const int wid  = threadIdx.x >> 6;
    const int lane = threadIdx.x & 63;
    const int n    = blockIdx.x * 4 + wid;

    const int p0  = ptr[n];
    const int deg = ptr[n + 1] - p0;
    float* wl = w_lds[wid];
    int*   sl = s_lds[wid];
    const ushort* fb = (const ushort*)featb;

    if (deg <= MAXD_LDS) {
        // ---- phase 1: weights, one lane per (edge, head) ----
        const int eo = lane >> 2;          // edge in group of 16
        const int hA = lane & 3;           // head
        const float er_n = er[n * HEADS + hA];
        const float g0 = ee[hA], g1 = ee[HEADS + hA], g2 = ee[2 * HEADS + hA];

        float zacc = 0.f;
        for (int i0 = 0; i0 < deg; i0 += 16) {
            const int idx = i0 + eo;
            float w = 0.f;
            if (idx < deg) {
                const int2 sc = sc_csr[p0 + idx];
                const int ty = sc.y >> 24;
                float s = el[sc.x * HEADS + hA] + er_n +
                          ((ty == 0) ? g0 : ((ty == 1) ? g1 : g2));
                s = s > 0.f ? s : NEG_SLOPE * s;
                w = __expf(s);
                wl[idx * HEADS + hA] = w;
                if (hA == 0) sl[idx] = sc.x;
            }
            zacc += w;
        }
        // reduce z over edge groups (lane bits 2..5); lane then holds z[hA]
        zacc += __shfl_xor(zacc, 4, 64);
        zacc += __shfl_xor(zacc, 8, 64);
        zacc += __shfl_xor(zacc, 16, 64);
        zacc += __shfl_xor(zacc, 32, 64);
        if (lane < 4)
            invz[n * HEADS + lane] = (deg > 0) ? __frcp_rn(zacc) : 0.f;

        // ---- phase 2: accumulate, quarter-wave per edge ----
        const int q  = lane >> 4;          // which edge of the 4 in flight
        const int c  = lane & 15;          // cols 4c..4c+3
        const int hB = c >> 2;             // head of those cols
        const float inv_z = (deg > 0) ? __frcp_rn(__shfl(zacc, hB, 64)) : 0.f;

        float a0 = 0.f, a1 = 0.f, a2 = 0.f, a3 = 0.f;
        int i = 0;
        for (; i + 8 <= deg; i += 8) {
            const int idxA = i + q, idxB = i + 4 + q;
            const int sA = sl[idxA], sB = sl[idxB];
            const float wA = wl[idxA * HEADS + hB];
            const float wB = wl[idxB * HEADS + hB];
            const uint2 fA = *(const uint2*)(fb + ((size_t)sA << 6) + (c << 2));
            const uint2 fB = *(const uint2*)(fb + ((size_t)sB << 6) + (c << 2));
            a0 += __uint_as_float(fA.x << 16) * wA + __uint_as_float(fB.x << 16) * wB;
            a1 += __uint_as_float(fA.x & 0xFFFF0000u) * wA + __uint_as_float(fB.x & 0xFFFF0000u) * wB;
            a2 += __uint_as_float(fA.y << 16) * wA + __uint_as_float(fB.y << 16) * wB;
            a3 += __uint_as_float(fA.y & 0xFFFF0000u) * wA + __uint_as_float(fB.y & 0xFFFF0000u) * wB;
        }
        for (; i < deg; i += 4) {
            const int idx = i + q;
            if (idx < deg) {
                const int sA = sl[idx];
                const float wA = wl[idx * HEADS + hB];
                const uint2 fA = *(const uint2*)(fb + ((size_t)sA << 6) + (c << 2));
                a0 += __uint_as_float(fA.x << 16) * wA;
                a1 += __uint_as_float(fA.x & 0xFFFF0000u) * wA;
                a2 += __uint_as_float(fA.y << 16) * wA;
                a3 += __uint_as_float(fA.y & 0xFFFF0000u) * wA;
            }
        }
        // reduce over the 4 edge slots (lane bits 4..5)
        a0 += __shfl_xor(a0, 16, 64); a0 += __shfl_xor(a0, 32, 64);
        a1 += __shfl_xor(a1, 16, 64); a1 += __shfl_xor(a1, 32, 64);
        a2 += __shfl_xor(a2, 16, 64); a2 += __shfl_xor(a2, 32, 64);
        a3 += __shfl_xor(a3, 16, 64); a3 += __shfl_xor(a3, 32, 64);
        if (q == 0) {
            f32x4 v = {a0 * inv_z, a1 * inv_z, a2 * inv_z, a3 * inv_z};
            *(f32x4*)(rst + (size_t)n * HD + (c << 2)) = v;
        }
    } else {
        // ---- rare big-degree path: two passes, recompute ----
        const int hA = lane & 3;
        const int eo = lane >> 2;
        const float er_nA = er[n * HEADS + hA];
        const float a0 = ee[hA], a1 = ee[HEADS + hA], a2 = ee[2 * HEADS + hA];
        float zacc = 0.f;
        for (int base = 0; base < deg; base += 16) {
            const int idx = base + eo;
            if (idx < deg) {
                const int2 sc = sc_csr[p0 + idx];
                const int ty = sc.y >> 24;
                float s = el[sc.x * HEADS + hA] + er_nA + ((ty == 0) ? a0 : ((ty == 1) ? a1 : a2));
                s = s > 0.f ? s : NEG_SLOPE * s;
                zacc += __expf(s);
            }
        }
#pragma unroll
        for (int m = 4; m < 64; m <<= 1) zacc += __shfl_xor(zacc, m, 64);
        if (lane < 4) invz[n * HEADS + lane] = __frcp_rn(zacc);
        const int h = lane >> 4;
        const float inv_z = __frcp_rn(__shfl(zacc, h, 64));
        const float er_n = er[n * HEADS + h];
        const float g0 = ee[h], g1 = ee[HEADS + h], g2 = ee[2 * HEADS + h];
        float racc = 0.f;
        for (int i = 0; i < deg; ++i) {
            const int2 sc = sc_csr[p0 + i];
            const int ty = sc.y >> 24;
            float s = el[sc.x * HEADS + h] + er_n + ((ty == 0) ? g0 : ((ty == 1) ? g1 : g2));
            s = s > 0.f ? s : NEG_SLOPE * s;
            const float a = __expf(s) * inv_z;
            racc += __bfloat162float(featb[(size_t)sc.x * HD + lane]) * a;
        }
        rst[(size_t)n * HD + lane] = racc;
    }
}

// ---------------------------------------------------------------------------
// Kernel D: a_out in ORIGINAL edge order — fully coalesced float4 writes.
// Recomputes w from L2-resident el/er/ee (1.6 MB each) + invz gather.
// ---------------------------------------------------------------------------
__global__ __launch_bounds__(256) void attn_out_kernel(
    const int* __restrict__ src, const int* __restrict__ dst,
    const int* __restrict__ etype,
    const float* __restrict__ el, const float* __restrict__ er,
    const float* __restrict__ ee, const float* __restrict__ invz,
    float* __restrict__ a_out)
{
    const int e = blockIdx.x * 256 + threadIdx.x;   // grid exact: E/256
    const int sN = src[e];
    const int dN = dst[e];
    const int ty = etype[e];
    const float4 l4 = *(const float4*)(el + (size_t)sN * HEADS);
    const float4 r4 = *(const float4*)(er + (size_t)dN * HEADS);
    const float4 g4 = *(const float4*)(ee + (size_t)ty * HEADS);
    const float4 iz = *(const float4*)(invz + (size_t)dN * HEADS);
    float4 a;
    float s;
    s = l4.x + r4.x + g4.x; s = s > 0.f ? s : NEG_SLOPE * s; a.x = __expf(s) * iz.x;
    s = l4.y + r4.y + g4.y; s = s > 0.f ? s : NEG_SLOPE * s; a.y = __expf(s) * iz.y;
    s = l4.z + r4.z + g4.z; s = s > 0.f ? s : NEG_SLOPE * s; a.z = __expf(s) * iz.z;
    s = l4.w + r4.w + g4.w; s = s > 0.f ? s : NEG_SLOPE * s; a.w = __expf(s) * iz.w;
    *(float4*)(a_out + (size_t)e * HEADS) = a;
}

extern "C" void kernel_launch(void* const* d_in, const int* in_sizes, int n_in,
                              void* d_out, int out_size, void* d_ws, size_t ws_size,
                              hipStream_t stream)
{
    const float* x        = (const float*)d_in[0];
    const float* W        = (const float*)d_in[1];
    const float* W_e      = (const float*)d_in[2];
    const float* attn_l   = (const float*)d_in[3];
    const float* attn_r   = (const float*)d_in[4];
    const float* attn_e   = (const float*)d_in[5];
    const float* edge_emb = (const float*)d_in[6];
    const int* src   = (const int*)d_in[7];
    const int* dst   = (const int*)d_in[8];
    const int* etype = (const int*)d_in[9];

    float* out     = (float*)d_out;
    float* rst_out = out;                              // N*H*D
    float* a_out   = out + (size_t)N_NODES * HD;       // E*H

    char* w = (char*)d_ws;
    __hip_bfloat16* featb = (__hip_bfloat16*)w; w += (size_t)N_NODES * HD * 2;   // 12.8 MB
    float* el    = (float*)w;  w += (size_t)N_NODES * HEADS * 4;    //  1.6 MB
    float* er    = (float*)w;  w += (size_t)N_NODES * HEADS * 4;    //  1.6 MB
    float* ee    = (float*)w;  w += 64;
    int*   ptr   = (int*)w;    w += (size_t)(N_NODES + 4) * 4;      //  0.4 MB
    int*   bhist = (int*)w;    w += (size_t)PBLK * NBUCK * 4;       //  1.28 MB
    int*   btot  = (int*)w;    w += (size_t)NBUCK * 4;
    int*   bbase = (int*)w;    w += (size_t)(NBUCK + 4) * 4;
    short* WTb   = (short*)w;  w += (size_t)HD * IN_FEATS * 2;      //   16 KB
    int2*  sc_bucket = (int2*)w; w += (size_t)N_EDGES * 8;          // 12.8 MB
    int2*  sc_csr    = (int2*)w; w += (size_t)N_EDGES * 8;          // 12.8 MB

    // invz aliases sc_bucket: sc_bucket is dead after bucket_csr_kernel,
    // and agg/attn_out run strictly after it. Keeps ws footprint identical
    // to the known-good 288us kernel (no growth past ws_size).
    float* invz = (float*)sc_bucket;                   // 1.6 MB of 12.8 MB

    wt_prep_kernel<<<(IN_FEATS * HD) / 256, 256, 0, stream>>>(W, WTb);
    feat_el_er_kernel<<<N_NODES / 16, 256, 0, stream>>>(
        x, WTb, attn_l, attn_r, featb, el, er);
    ee_kernel<<<N_ETYPES * HEADS, 64, 0, stream>>>(edge_emb, W_e, attn_e, ee);

    bucket_hist_kernel<<<PBLK, 256, 0, stream>>>(dst, bhist);
    bucket_scan1_kernel<<<NBUCK, 256, 0, stream>>>(bhist, btot);
    bucket_scan2_kernel<<<1, 1024, 0, stream>>>(btot, bbase);
    bucket_scatter_kernel<<<PBLK, 256, 0, stream>>>(src, dst, etype, bhist, bbase, sc_bucket);
    bucket_csr_kernel<<<NBUCK, 256, 0, stream>>>(sc_bucket, bbase, ptr, sc_csr);

    agg_kernel<<<N_NODES / 4, 256, 0, stream>>>(
        sc_csr, ptr, el, er, ee, featb, rst_out, invz);
    attn_out_kernel<<<N_EDGES / 256, 256, 0, stream>>>(
        src, dst, etype, el, er, ee, invz, a_out);
}

// Round 3
// 287.933 us; speedup vs baseline: 1.0054x; 1.0054x over previous
//
#include <hip/hip_runtime.h>
#include <hip/hip_bf16.h>

#define N_NODES   100000
#define N_EDGES   1600000
#define N_ETYPES  3
#define IN_FEATS  128
#define HEADS     4
#define OUT_FEATS 16
#define EDGE_FEATS 64
#define HD        64            // HEADS*OUT_FEATS
#define NEG_SLOPE 0.2f
#define MAXD_LDS  128           // agg fast-path max degree (Poisson(16): P(>128)~0)

#define NBUCK     800           // buckets for counting sort
#define NPB       125           // nodes per bucket (800*125 = N_NODES)
#define PBLK      400           // blocks in hist/scatter passes
#define EPB       4000          // edges per block (400*4000 = N_EDGES)
#define BCAP      2560          // LDS stage capacity in bucket_csr (mean 2000, std ~45)

// packed edge payload: src(17b) | ty(2b)<<17 | ldst(7b)<<19  — 26 bits.
// original edge index NOT stored: a_out is rebuilt in original order.

typedef short s16x8 __attribute__((ext_vector_type(8)));
typedef float f32x4 __attribute__((ext_vector_type(4)));

__device__ __forceinline__ short f2bs(float f) {
    __hip_bfloat16 h = __float2bfloat16(f);
    return *reinterpret_cast<short*>(&h);
}

// ---------------------------------------------------------------------------
// Prep: WT bf16 [64][128]  (WT[n][k] = W[k][n])
// ---------------------------------------------------------------------------
__global__ __launch_bounds__(256) void wt_prep_kernel(
    const float* __restrict__ W, short* __restrict__ WTb)
{
    const int t = blockIdx.x * 256 + threadIdx.x;   // 0..8191
    const int k = t >> 6, n = t & 63;
    WTb[n * IN_FEATS + k] = f2bs(W[t]);
}

// ---------------------------------------------------------------------------
// Kernel A (MFMA): feat = x @ W, bf16 store, fused el/er.
// er goes into eriz[n*8 + h] (stride-8 interleave with invz at +4).
// ---------------------------------------------------------------------------
#define XS_STRIDE 136   // 128 + 8 pad shorts
__global__ __launch_bounds__(256) void feat_el_er_kernel(
    const float* __restrict__ x,
    const short* __restrict__ WTb,
    const float* __restrict__ attn_l,
    const float* __restrict__ attn_r,
    __hip_bfloat16* __restrict__ featb,
    float* __restrict__ el,
    float* __restrict__ eriz)
{
    __shared__ short Xs[16 * XS_STRIDE];
    __shared__ short Ws[64 * XS_STRIDE];

    const int t = threadIdx.x;
    const int row0 = blockIdx.x * 16;
    {   // stage x -> bf16 LDS
        const int r = t >> 4, k0 = (t & 15) * 8;
        const float4* xg = (const float4*)(x + (size_t)(row0 + r) * IN_FEATS + k0);
        const float4 v0 = xg[0], v1 = xg[1];
        s16x8 p;
        p[0] = f2bs(v0.x); p[1] = f2bs(v0.y); p[2] = f2bs(v0.z); p[3] = f2bs(v0.w);
        p[4] = f2bs(v1.x); p[5] = f2bs(v1.y); p[6] = f2bs(v1.z); p[7] = f2bs(v1.w);
        *(s16x8*)&Xs[r * XS_STRIDE + k0] = p;
    }
    {   // stage WT bf16
#pragma unroll
        for (int j = 0; j < 4; ++j) {
            const int u = t + 256 * j;
            const int r = u >> 4, c = (u & 15) * 8;
            *(s16x8*)&Ws[r * XS_STRIDE + c] = *(const s16x8*)(WTb + r * IN_FEATS + c);
        }
    }
    __syncthreads();

    const int w    = t >> 6;
    const int lane = t & 63;
    const int m    = lane & 15;
    const int q    = lane >> 4;

    f32x4 acc = {0.f, 0.f, 0.f, 0.f};
#pragma unroll
    for (int kb = 0; kb < 4; ++kb) {
        const s16x8 af = *(const s16x8*)&Xs[m * XS_STRIDE + kb * 32 + q * 8];
        const s16x8 bf = *(const s16x8*)&Ws[(w * 16 + m) * XS_STRIDE + kb * 32 + q * 8];
        acc = __builtin_amdgcn_mfma_f32_16x16x32_bf16(af, bf, acc, 0, 0, 0);
    }

    const float al = attn_l[w * OUT_FEATS + m];
    const float ar = attn_r[w * OUT_FEATS + m];
#pragma unroll
    for (int r = 0; r < 4; ++r) {
        const int row = row0 + q * 4 + r;
        featb[(size_t)row * HD + w * 16 + m] = __float2bfloat16(acc[r]);
        float cl = acc[r] * al;
        float cr = acc[r] * ar;
#pragma unroll
        for (int msk = 1; msk < 16; msk <<= 1) {
            cl += __shfl_xor(cl, msk, 64);
            cr += __shfl_xor(cr, msk, 64);
        }
        if (m == 0) {
            el[row * HEADS + w] = cl;
            eriz[(size_t)row * 8 + w] = cr;
        }
    }
}

// ---------------------------------------------------------------------------
// Kernel B: ee[t,h] (12 scalars)
// ---------------------------------------------------------------------------
__global__ __launch_bounds__(64) void ee_kernel(
    const float* __restrict__ edge_emb,
    const float* __restrict__ W_e,
    const float* __restrict__ attn_e,
    float* __restrict__ ee)
{
    const int b  = blockIdx.x;
    const int ty = b >> 2;
    const int h  = b & 3;
    const int e  = threadIdx.x;

    float ef = 0.f;
#pragma unroll
    for (int k = 0; k < EDGE_FEATS; ++k)
        ef += edge_emb[ty * EDGE_FEATS + k] *
              W_e[k * (HEADS * EDGE_FEATS) + h * EDGE_FEATS + e];
    float v = ef * attn_e[h * EDGE_FEATS + e];
#pragma unroll
    for (int m = 1; m < 64; m <<= 1) v += __shfl_xor(v, m, 64);
    if (e == 0) ee[ty * HEADS + h] = v;
}

// ---------------------------------------------------------------------------
// CSR build via bucketed counting sort — all hot atomics in LDS.
// ---------------------------------------------------------------------------
__global__ __launch_bounds__(256) void bucket_hist_kernel(
    const int* __restrict__ dst, int* __restrict__ bhist)
{
    __shared__ int h[NBUCK];
    const int t = threadIdx.x, b = blockIdx.x;
    for (int j = t; j < NBUCK; j += 256) h[j] = 0;
    __syncthreads();
    const int e0 = b * EPB;
    for (int i = t; i < EPB; i += 256)
        atomicAdd(&h[dst[e0 + i] / NPB], 1);
    __syncthreads();
    for (int j = t; j < NBUCK; j += 256) bhist[b * NBUCK + j] = h[j];
}

// per bucket j, exclusive scan over blocks; btot[j] = total.
__global__ __launch_bounds__(256) void bucket_scan1_kernel(
    int* __restrict__ bhist, int* __restrict__ btot)
{
    __shared__ int sh[PBLK];
    const int t = threadIdx.x, j = blockIdx.x;
    const int j0 = t, j1 = t + 256;
    int o0 = 0, o1 = 0;
    if (j0 < PBLK) { o0 = bhist[j0 * NBUCK + j]; sh[j0] = o0; }
    if (j1 < PBLK) { o1 = bhist[j1 * NBUCK + j]; sh[j1] = o1; }
    __syncthreads();
    for (int off = 1; off < PBLK; off <<= 1) {
        int v0 = (j0 >= off && j0 < PBLK) ? sh[j0 - off] : 0;
        int v1 = (j1 >= off && j1 < PBLK) ? sh[j1 - off] : 0;
        __syncthreads();
        if (j0 < PBLK) sh[j0] += v0;
        if (j1 < PBLK) sh[j1] += v1;
        __syncthreads();
    }
    if (j0 < PBLK) bhist[j0 * NBUCK + j] = sh[j0] - o0;
    if (j1 < PBLK) bhist[j1 * NBUCK + j] = sh[j1] - o1;
    if (t == 255) btot[j] = sh[PBLK - 1];
}

// single block: exclusive scan btot[NBUCK] -> bbase[NBUCK+1]
__global__ __launch_bounds__(1024) void bucket_scan2_kernel(
    const int* __restrict__ btot, int* __restrict__ bbase)
{
    __shared__ int sh[NBUCK];
    const int t = threadIdx.x;
    int o = 0;
    if (t < NBUCK) { o = btot[t]; sh[t] = o; }
    __syncthreads();
    for (int off = 1; off < NBUCK; off <<= 1) {
        int v = (t >= off && t < NBUCK) ? sh[t - off] : 0;
        __syncthreads();
        if (t < NBUCK) sh[t] += v;
        __syncthreads();
    }
    if (t < NBUCK) bbase[t] = sh[t] - o;
    if (t == NBUCK - 1) bbase[NBUCK] = sh[t];
}

// scatter edges into bucket regions; LDS running counters.
// payload (int): src | ty<<17 | ldst<<19
__global__ __launch_bounds__(256) void bucket_scatter_kernel(
    const int* __restrict__ src, const int* __restrict__ dst,
    const int* __restrict__ etype,
    const int* __restrict__ bhist, const int* __restrict__ bbase,
    int* __restrict__ sc_bucket)
{
    __shared__ int cnt[NBUCK];
    const int t = threadIdx.x, b = blockIdx.x;
    for (int j = t; j < NBUCK; j += 256)
        cnt[j] = bbase[j] + bhist[b * NBUCK + j];
    __syncthreads();
    const int e0 = b * EPB;
    for (int i = t; i < EPB; i += 256) {
        const int e  = e0 + i;
        const int dn = dst[e];
        const int bu = dn / NPB;
        const int ld = dn - bu * NPB;
        const int slot = atomicAdd(&cnt[bu], 1);
        sc_bucket[slot] = src[e] | (etype[e] << 17) | (ld << 19);
    }
}

// one block per bucket: LDS-stage edges (single global read), bin over 125
// local nodes in LDS, emit ptr + final CSR int {src | ty<<17}.
__global__ __launch_bounds__(256) void bucket_csr_kernel(
    const int* __restrict__ sc_bucket, const int* __restrict__ bbase,
    int* __restrict__ ptr, int* __restrict__ sc_csr)
{
    __shared__ int sbuf[BCAP];       // 10 KB
    __shared__ int sdeg[128];
    __shared__ int scur[128];
    const int t = threadIdx.x, b = blockIdx.x;
    const int lo = bbase[b];
    const int count = bbase[b + 1] - lo;
    const bool staged = (count <= BCAP);

    if (t < 128) sdeg[t] = 0;
    __syncthreads();
    if (staged) {
        for (int i = t; i < count; i += 256) {
            const int v = sc_bucket[lo + i];
            sbuf[i] = v;
            atomicAdd(&sdeg[(v >> 19) & 0x7F], 1);
        }
    } else {
        for (int i = t; i < count; i += 256)
            atomicAdd(&sdeg[(sc_bucket[lo + i] >> 19) & 0x7F], 1);
    }
    __syncthreads();
    // exclusive scan over 128 (125 used)
    const int orig = (t < 128) ? sdeg[t] : 0;
    for (int off = 1; off < 128; off <<= 1) {
        const int v = (t < 128 && t >= off) ? sdeg[t - off] : 0;
        __syncthreads();
        if (t < 128) sdeg[t] += v;
        __syncthreads();
    }
    if (t < 128) {
        const int excl = sdeg[t] - orig;
        if (t < NPB) ptr[b * NPB + t] = lo + excl;
        scur[t] = lo + excl;             // global slot base
    }
    if (b == 0 && t == 0) ptr[N_NODES] = N_EDGES;
    __syncthreads();
    if (staged) {
        for (int i = t; i < count; i += 256) {
            const int v = sbuf[i];
            const int ld = (v >> 19) & 0x7F;
            const int slot = atomicAdd(&scur[ld], 1);
            sc_csr[slot] = v & 0x7FFFF;          // src | ty<<17
        }
    } else {
        for (int i = t; i < count; i += 256) {
            const int v = sc_bucket[lo + i];
            const int ld = (v >> 19) & 0x7F;
            const int slot = atomicAdd(&scur[ld], 1);
            sc_csr[slot] = v & 0x7FFFF;
        }
    }
}

// ---------------------------------------------------------------------------
// Kernel C: per-dst aggregation, one wave per node, two in-wave phases.
// Phase 1: 1 lane per (edge,head): exp ONCE per (e,h); w,src -> LDS; z reduce.
// Phase 2: 8 edges x 8 lanes, 16B dwordx4 feat loads, w broadcast from LDS.
// invz written into eriz[n*8+4..7] (shares cacheline with er for attn_out).
// ---------------------------------------------------------------------------
__global__ __launch_bounds__(256) void agg_kernel(
    const int* __restrict__ sc_csr, const int* __restrict__ ptr,
    const float* __restrict__ el, float* __restrict__ eriz,
    const float* __restrict__ ee, const __hip_bfloat16* __restrict__ featb,
    float* __restrict__ rst)
{
    __shared__ float w_lds[4][MAXD_LDS * HEADS];   // 8 KB
    __shared__ int   s_lds[4][MAXD_LDS];           // 2 KB
    const int wid  = threadIdx.x >> 6;
    const int lane = threadIdx.x & 63;
    const int n    = blockIdx.x * 4 + wid;

    const int p0  = ptr[n];
    const int deg = ptr[n + 1] - p0;
    float* wl = w_lds[wid];
    int*   sl = s_lds[wid];
    const ushort* fb = (const ushort*)featb;

    if (deg <= MAXD_LDS) {
        // ---- phase 1: weights, one lane per (edge, head) ----
        const int eo = lane >> 2;          // edge in group of 16
        const int hA = lane & 3;           // head
        const float er_n = eriz[(size_t)n * 8 + hA];
        const float g0 = ee[hA], g1 = ee[HEADS + hA], g2 = ee[2 * HEADS + hA];

        float zacc = 0.f;
        for (int i0 = 0; i0 < deg; i0 += 16) {
            const int idx = i0 + eo;
            if (idx < deg) {
                const int v  = sc_csr[p0 + idx];
                const int sn = v & 0x1FFFF;
                const int ty = v >> 17;
                float s = el[sn * HEADS + hA] + er_n +
                          ((ty == 0) ? g0 : ((ty == 1) ? g1 : g2));
                s = s > 0.f ? s : NEG_SLOPE * s;
                const float w = __expf(s);
                wl[idx * HEADS + hA] = w;
                if (hA == 0) sl[idx] = sn;
                zacc += w;
            }
        }
        // reduce z over edge groups (lane bits 2..5); lane then holds z[lane&3]
        zacc += __shfl_xor(zacc, 4, 64);
        zacc += __shfl_xor(zacc, 8, 64);
        zacc += __shfl_xor(zacc, 16, 64);
        zacc += __shfl_xor(zacc, 32, 64);
        if (lane < 4)
            eriz[(size_t)n * 8 + 4 + lane] = (deg > 0) ? __frcp_rn(zacc) : 0.f;

        // ---- phase 2: accumulate, 8 edges x 8 lanes, 16B loads ----
        const int q8 = lane >> 3;          // edge slot 0..7
        const int c8 = lane & 7;           // col group: cols 8*c8 .. 8*c8+7
        const int h8 = c8 >> 1;            // head of those cols
        const float inv_z = (deg > 0) ? __frcp_rn(__shfl(zacc, h8, 64)) : 0.f;

        float a0 = 0.f, a1 = 0.f, a2 = 0.f, a3 = 0.f;
        float a4 = 0.f, a5 = 0.f, a6 = 0.f, a7 = 0.f;
        int i = 0;
        for (; i + 8 <= deg; i += 8) {
            const int idx = i + q8;
            const int sA = sl[idx];
            const float wA = wl[idx * HEADS + h8];
            const uint4 fA = *(const uint4*)(fb + ((size_t)sA << 6) + (c8 << 3));
            a0 += __uint_as_float(fA.x << 16) * wA;
            a1 += __uint_as_float(fA.x & 0xFFFF0000u) * wA;
            a2 += __uint_as_float(fA.y << 16) * wA;
            a3 += __uint_as_float(fA.y & 0xFFFF0000u) * wA;
            a4 += __uint_as_float(fA.z << 16) * wA;
            a5 += __uint_as_float(fA.z & 0xFFFF0000u) * wA;
            a6 += __uint_as_float(fA.w << 16) * wA;
            a7 += __uint_as_float(fA.w & 0xFFFF0000u) * wA;
        }
        if (i + q8 < deg) {                // tail (<8 edges), one guarded step
            const int idx = i + q8;
            const int sA = sl[idx];
            const float wA = wl[idx * HEADS + h8];
            const uint4 fA = *(const uint4*)(fb + ((size_t)sA << 6) + (c8 << 3));
            a0 += __uint_as_float(fA.x << 16) * wA;
            a1 += __uint_as_float(fA.x & 0xFFFF0000u) * wA;
            a2 += __uint_as_float(fA.y << 16) * wA;
            a3 += __uint_as_float(fA.y & 0xFFFF0000u) * wA;
            a4 += __uint_as_float(fA.z << 16) * wA;
            a5 += __uint_as_float(fA.z & 0xFFFF0000u) * wA;
            a6 += __uint_as_float(fA.w << 16) * wA;
            a7 += __uint_as_float(fA.w & 0xFFFF0000u) * wA;
        }
        // reduce over the 8 edge slots (lane bits 3..5)
        a0 += __shfl_xor(a0, 8, 64); a0 += __shfl_xor(a0, 16, 64); a0 += __shfl_xor(a0, 32, 64);
        a1 += __shfl_xor(a1, 8, 64); a1 += __shfl_xor(a1, 16, 64); a1 += __shfl_xor(a1, 32, 64);
        a2 += __shfl_xor(a2, 8, 64); a2 += __shfl_xor(a2, 16, 64); a2 += __shfl_xor(a2, 32, 64);
        a3 += __shfl_xor(a3, 8, 64); a3 += __shfl_xor(a3, 16, 64); a3 += __shfl_xor(a3, 32, 64);
        a4 += __shfl_xor(a4, 8, 64); a4 += __shfl_xor(a4, 16, 64); a4 += __shfl_xor(a4, 32, 64);
        a5 += __shfl_xor(a5, 8, 64); a5 += __shfl_xor(a5, 16, 64); a5 += __shfl_xor(a5, 32, 64);
        a6 += __shfl_xor(a6, 8, 64); a6 += __shfl_xor(a6, 16, 64); a6 += __shfl_xor(a6, 32, 64);
        a7 += __shfl_xor(a7, 8, 64); a7 += __shfl_xor(a7, 16, 64); a7 += __shfl_xor(a7, 32, 64);
        if (q8 == 0) {
            f32x4 v0 = {a0 * inv_z, a1 * inv_z, a2 * inv_z, a3 * inv_z};
            f32x4 v1 = {a4 * inv_z, a5 * inv_z, a6 * inv_z, a7 * inv_z};
            *(f32x4*)(rst + (size_t)n * HD + (c8 << 3))     = v0;
            *(f32x4*)(rst + (size_t)n * HD + (c8 << 3) + 4) = v1;
        }
    } else {
        // ---- rare big-degree path: two passes, recompute ----
        const int hA = lane & 3;
        const int eo = lane >> 2;
        const float er_nA = eriz[(size_t)n * 8 + hA];
        const float a0 = ee[hA], a1 = ee[HEADS + hA], a2 = ee[2 * HEADS + hA];
        float zacc = 0.f;
        for (int base = 0; base < deg; base += 16) {
            const int idx = base + eo;
            if (idx < deg) {
                const int v  = sc_csr[p0 + idx];
                const int sn = v & 0x1FFFF;
                const int ty = v >> 17;
                float s = el[sn * HEADS + hA] + er_nA + ((ty == 0) ? a0 : ((ty == 1) ? a1 : a2));
                s = s > 0.f ? s : NEG_SLOPE * s;
                zacc += __expf(s);
            }
        }
#pragma unroll
        for (int m = 4; m < 64; m <<= 1) zacc += __shfl_xor(zacc, m, 64);
        if (lane < 4) eriz[(size_t)n * 8 + 4 + lane] = __frcp_rn(zacc);
        const int h = lane >> 4;
        const float inv_z = __frcp_rn(__shfl(zacc, h, 64));
        const float er_n = eriz[(size_t)n * 8 + h];
        const float g0 = ee[h], g1 = ee[HEADS + h], g2 = ee[2 * HEADS + h];
        float racc = 0.f;
        for (int i = 0; i < deg; ++i) {
            const int v  = sc_csr[p0 + i];
            const int sn = v & 0x1FFFF;
            const int ty = v >> 17;
            float s = el[sn * HEADS + h] + er_n + ((ty == 0) ? g0 : ((ty == 1) ? g1 : g2));
            s = s > 0.f ? s : NEG_SLOPE * s;
            const float a = __expf(s) * inv_z;
            racc += __bfloat162float(featb[(size_t)sn * HD + lane]) * a;
        }
        rst[(size_t)n * HD + lane] = racc;
    }
}

// ---------------------------------------------------------------------------
// Kernel D: a_out in ORIGINAL edge order — fully coalesced float4 writes.
// er+invz share one 32B cacheline per node (eriz).
// ---------------------------------------------------------------------------
__global__ __launch_bounds__(256) void attn_out_kernel(
    const int* __restrict__ src, const int* __restrict__ dst,
    const int* __restrict__ etype,
    const float* __restrict__ el, const float* __restrict__ eriz,
    const float* __restrict__ ee,
    float* __restrict__ a_out)
{
    const int e = blockIdx.x * 256 + threadIdx.x;   // grid exact: E/256
    const int sN = src[e];
    const int dN = dst[e];
    const int ty = etype[e];
    const float4 l4 = *(const float4*)(el + (size_t)sN * HEADS);
    const float4 r4 = *(const float4*)(eriz + (size_t)dN * 8);
    const float4 iz = *(const float4*)(eriz + (size_t)dN * 8 + 4);
    const float4 g4 = *(const float4*)(ee + (size_t)ty * HEADS);
    float4 a;
    float s;
    s = l4.x + r4.x + g4.x; s = s > 0.f ? s : NEG_SLOPE * s; a.x = __expf(s) * iz.x;
    s = l4.y + r4.y + g4.y; s = s > 0.f ? s : NEG_SLOPE * s; a.y = __expf(s) * iz.y;
    s = l4.z + r4.z + g4.z; s = s > 0.f ? s : NEG_SLOPE * s; a.z = __expf(s) * iz.z;
    s = l4.w + r4.w + g4.w; s = s > 0.f ? s : NEG_SLOPE * s; a.w = __expf(s) * iz.w;
    *(float4*)(a_out + (size_t)e * HEADS) = a;
}

extern "C" void kernel_launch(void* const* d_in, const int* in_sizes, int n_in,
                              void* d_out, int out_size, void* d_ws, size_t ws_size,
                              hipStream_t stream)
{
    const float* x        = (const float*)d_in[0];
    const float* W        = (const float*)d_in[1];
    const float* W_e      = (const float*)d_in[2];
    const float* attn_l   = (const float*)d_in[3];
    const float* attn_r   = (const float*)d_in[4];
    const float* attn_e   = (const float*)d_in[5];
    const float* edge_emb = (const float*)d_in[6];
    const int* src   = (const int*)d_in[7];
    const int* dst   = (const int*)d_in[8];
    const int* etype = (const int*)d_in[9];

    float* out     = (float*)d_out;
    float* rst_out = out;                              // N*H*D
    float* a_out   = out + (size_t)N_NODES * HD;       // E*H

    char* w = (char*)d_ws;
    __hip_bfloat16* featb = (__hip_bfloat16*)w; w += (size_t)N_NODES * HD * 2;   // 12.8 MB
    float* el    = (float*)w;  w += (size_t)N_NODES * HEADS * 4;    //  1.6 MB
    float* eriz  = (float*)w;  w += (size_t)N_NODES * 8 * 4;        //  3.2 MB (er|invz)
    float* ee    = (float*)w;  w += 64;
    int*   ptr   = (int*)w;    w += (size_t)(N_NODES + 4) * 4;      //  0.4 MB
    int*   bhist = (int*)w;    w += (size_t)PBLK * NBUCK * 4;       //  1.28 MB
    int*   btot  = (int*)w;    w += (size_t)NBUCK * 4;
    int*   bbase = (int*)w;    w += (size_t)(NBUCK + 4) * 4;
    short* WTb   = (short*)w;  w += (size_t)HD * IN_FEATS * 2;      //   16 KB
    int*   sc_bucket = (int*)w; w += (size_t)N_EDGES * 4;           //  6.4 MB
    int*   sc_csr    = (int*)w; w += (size_t)N_EDGES * 4;           //  6.4 MB
    // total ~32 MB (was ~43 MB in the known-good 288us version)

    wt_prep_kernel<<<(IN_FEATS * HD) / 256, 256, 0, stream>>>(W, WTb);
    feat_el_er_kernel<<<N_NODES / 16, 256, 0, stream>>>(
        x, WTb, attn_l, attn_r, featb, el, eriz);
    ee_kernel<<<N_ETYPES * HEADS, 64, 0, stream>>>(edge_emb, W_e, attn_e, ee);

    bucket_hist_kernel<<<PBLK, 256, 0, stream>>>(dst, bhist);
    bucket_scan1_kernel<<<NBUCK, 256, 0, stream>>>(bhist, btot);
    bucket_scan2_kernel<<<1, 1024, 0, stream>>>(btot, bbase);
    bucket_scatter_kernel<<<PBLK, 256, 0, stream>>>(src, dst, etype, bhist, bbase, sc_bucket);
    bucket_csr_kernel<<<NBUCK, 256, 0, stream>>>(sc_bucket, bbase, ptr, sc_csr);

    agg_kernel<<<N_NODES / 4, 256, 0, stream>>>(
        sc_csr, ptr, el, eriz, ee, featb, rst_out);
    attn_out_kernel<<<N_EDGES / 256, 256, 0, stream>>>(
        src, dst, etype, el, eriz, ee, a_out);
}